// Round 1
// baseline (5943.201 us; speedup 1.0000x reference)
//
#include <hip/hip_runtime.h>

// 2-layer LSTM (H=50) + FC head, fused, fp32.
// B=4096, T=512. Grid = 256 blocks x 256 threads; NB=16 batch per block.
// Thread (j = tid&63, grp = tid>>6) owns hidden unit j's 4 gate rows for
// 4 batch elements; c1/c2 live in registers, h1/h2 double-buffered in LDS.
// All 3 recurrent/input weight matrices (200x50) are LDS-resident (KP=52 pad).

#define HID 50
#define GATES 200      // 4*HID
#define KP 52          // padded row length (multiple of 4, 16B-aligned rows)
#define SEQ 512
#define NB 16          // batch per block
#define NTHREADS 256
#define XT 32          // x time-tile staged in LDS

__device__ __forceinline__ float sigf(float x) {
    return 1.0f / (1.0f + __expf(-x));
}
__device__ __forceinline__ float tanh_fast(float x) {
    // tanh(x) = 2*sigmoid(2x) - 1 ; saturates correctly at +-1 (exp->inf -> 0)
    return 2.0f / (1.0f + __expf(-2.0f * x)) - 1.0f;
}

__global__ __launch_bounds__(NTHREADS, 1)
void lstm2_fc_kernel(const float* __restrict__ x,
                     const float* __restrict__ w_ih0,
                     const float* __restrict__ w_hh0,
                     const float* __restrict__ b_ih0,
                     const float* __restrict__ b_hh0,
                     const float* __restrict__ w_ih1,
                     const float* __restrict__ w_hh1,
                     const float* __restrict__ b_ih1,
                     const float* __restrict__ b_hh1,
                     const float* __restrict__ fc_w,
                     const float* __restrict__ fc_b,
                     float* __restrict__ out)
{
    extern __shared__ float smem[];
    float* w0  = smem;                   // [GATES][KP]  w_hh0
    float* w1  = w0 + GATES * KP;        // [GATES][KP]  w_ih1
    float* w2  = w1 + GATES * KP;        // [GATES][KP]  w_hh1
    float* h1b = w2 + GATES * KP;        // [2][NB][KP]
    float* h2b = h1b + 2 * NB * KP;      // [2][NB][KP]
    float* xs  = h2b + 2 * NB * KP;      // [NB][XT]

    const int tid = threadIdx.x;
    const int b0  = blockIdx.x * NB;

    // ---- stage weights into LDS (pad k=50,51 with zeros) ----
    for (int idx = tid; idx < GATES * KP; idx += NTHREADS) {
        const int r = idx / KP;
        const int k = idx - r * KP;
        const bool ok = (k < HID);
        w0[idx] = ok ? w_hh0[r * HID + k] : 0.0f;
        w1[idx] = ok ? w_ih1[r * HID + k] : 0.0f;
        w2[idx] = ok ? w_hh1[r * HID + k] : 0.0f;
    }
    // ---- zero both h buffers (pad columns stay zero forever) ----
    for (int idx = tid; idx < 2 * NB * KP; idx += NTHREADS) {
        h1b[idx] = 0.0f;
        h2b[idx] = 0.0f;
    }

    const int  jslot  = tid & 63;
    const int  grp    = tid >> 6;        // 0..3 -> batches grp*4 .. grp*4+3
    const bool active = (jslot < HID);
    const int  jj     = active ? jslot : 0;
    const int  r0 = jj, r1 = HID + jj, r2 = 2 * HID + jj, r3 = 3 * HID + jj;
    const int  bbase = grp * 4;

    // per-row constants (input-dim is 1, so layer1 x-term is a scalar weight)
    const float wx0 = w_ih0[r0], wx1 = w_ih0[r1], wx2 = w_ih0[r2], wx3 = w_ih0[r3];
    const float bA0 = b_ih0[r0] + b_hh0[r0];
    const float bA1 = b_ih0[r1] + b_hh0[r1];
    const float bA2 = b_ih0[r2] + b_hh0[r2];
    const float bA3 = b_ih0[r3] + b_hh0[r3];
    const float bB0 = b_ih1[r0] + b_hh1[r0];
    const float bB1 = b_ih1[r1] + b_hh1[r1];
    const float bB2 = b_ih1[r2] + b_hh1[r2];
    const float bB3 = b_ih1[r3] + b_hh1[r3];

    const float* w0r0 = w0 + r0 * KP; const float* w0r1 = w0 + r1 * KP;
    const float* w0r2 = w0 + r2 * KP; const float* w0r3 = w0 + r3 * KP;
    const float* w1r0 = w1 + r0 * KP; const float* w1r1 = w1 + r1 * KP;
    const float* w1r2 = w1 + r2 * KP; const float* w1r3 = w1 + r3 * KP;
    const float* w2r0 = w2 + r0 * KP; const float* w2r1 = w2 + r1 * KP;
    const float* w2r2 = w2 + r2 * KP; const float* w2r3 = w2 + r3 * KP;

    float c1[4] = {0.f, 0.f, 0.f, 0.f};
    float c2[4] = {0.f, 0.f, 0.f, 0.f};
    int cur = 0;

    for (int t = 0; t < SEQ; ++t) {
        if ((t & (XT - 1)) == 0) {
            // all threads already passed last step's barrier -> xs overwrite safe
            for (int idx = tid; idx < NB * XT; idx += NTHREADS) {
                const int bl = idx >> 5;
                const int tq = idx & (XT - 1);
                xs[bl * XT + tq] = x[(size_t)(b0 + bl) * SEQ + t + tq];
            }
            __syncthreads();  // publish xs (and, at t=0, weights + h zeros)
        }

        const float* h1c = h1b + cur * NB * KP;
        const float* h2c = h2b + cur * NB * KP;
        float*       h1n = h1b + (cur ^ 1) * NB * KP;
        float*       h2n = h2b + (cur ^ 1) * NB * KP;
        const int    tq  = t & (XT - 1);

        // ================= layer 1 =================
        float a0[4], a1[4], a2[4], a3[4];
#pragma unroll
        for (int b = 0; b < 4; ++b) {
            const float xv = xs[(bbase + b) * XT + tq];
            a0[b] = wx0 * xv + bA0;
            a1[b] = wx1 * xv + bA1;
            a2[b] = wx2 * xv + bA2;
            a3[b] = wx3 * xv + bA3;
        }
#pragma unroll
        for (int k = 0; k < KP; k += 4) {
            const float4 W0 = *(const float4*)(w0r0 + k);
            const float4 W1 = *(const float4*)(w0r1 + k);
            const float4 W2 = *(const float4*)(w0r2 + k);
            const float4 W3 = *(const float4*)(w0r3 + k);
#pragma unroll
            for (int b = 0; b < 4; ++b) {
                const float4 hv = *(const float4*)(h1c + (bbase + b) * KP + k);
                a0[b] += W0.x * hv.x + W0.y * hv.y + W0.z * hv.z + W0.w * hv.w;
                a1[b] += W1.x * hv.x + W1.y * hv.y + W1.z * hv.z + W1.w * hv.w;
                a2[b] += W2.x * hv.x + W2.y * hv.y + W2.z * hv.z + W2.w * hv.w;
                a3[b] += W3.x * hv.x + W3.y * hv.y + W3.z * hv.z + W3.w * hv.w;
            }
        }
        float h1v[4];
#pragma unroll
        for (int b = 0; b < 4; ++b) {
            const float ig = sigf(a0[b]);
            const float fg = sigf(a1[b]);
            const float gg = tanh_fast(a2[b]);
            const float og = sigf(a3[b]);
            c1[b] = fg * c1[b] + ig * gg;
            h1v[b] = og * tanh_fast(c1[b]);
        }
        if (active) {
#pragma unroll
            for (int b = 0; b < 4; ++b) h1n[(bbase + b) * KP + jj] = h1v[b];
        }
        __syncthreads();  // publish h1[t]

        // ================= layer 2 =================
#pragma unroll
        for (int b = 0; b < 4; ++b) { a0[b] = bB0; a1[b] = bB1; a2[b] = bB2; a3[b] = bB3; }
#pragma unroll
        for (int k = 0; k < KP; k += 4) {
            const float4 U0 = *(const float4*)(w1r0 + k);
            const float4 U1 = *(const float4*)(w1r1 + k);
            const float4 U2 = *(const float4*)(w1r2 + k);
            const float4 U3 = *(const float4*)(w1r3 + k);
            const float4 V0 = *(const float4*)(w2r0 + k);
            const float4 V1 = *(const float4*)(w2r1 + k);
            const float4 V2 = *(const float4*)(w2r2 + k);
            const float4 V3 = *(const float4*)(w2r3 + k);
#pragma unroll
            for (int b = 0; b < 4; ++b) {
                const float4 p = *(const float4*)(h1n + (bbase + b) * KP + k);
                const float4 q = *(const float4*)(h2c + (bbase + b) * KP + k);
                a0[b] += U0.x * p.x + U0.y * p.y + U0.z * p.z + U0.w * p.w
                       + V0.x * q.x + V0.y * q.y + V0.z * q.z + V0.w * q.w;
                a1[b] += U1.x * p.x + U1.y * p.y + U1.z * p.z + U1.w * p.w
                       + V1.x * q.x + V1.y * q.y + V1.z * q.z + V1.w * q.w;
                a2[b] += U2.x * p.x + U2.y * p.y + U2.z * p.z + U2.w * p.w
                       + V2.x * q.x + V2.y * q.y + V2.z * q.z + V2.w * q.w;
                a3[b] += U3.x * p.x + U3.y * p.y + U3.z * p.z + U3.w * p.w
                       + V3.x * q.x + V3.y * q.y + V3.z * q.z + V3.w * q.w;
            }
        }
        float h2v[4];
#pragma unroll
        for (int b = 0; b < 4; ++b) {
            const float ig = sigf(a0[b]);
            const float fg = sigf(a1[b]);
            const float gg = tanh_fast(a2[b]);
            const float og = sigf(a3[b]);
            c2[b] = fg * c2[b] + ig * gg;
            h2v[b] = og * tanh_fast(c2[b]);
        }
        if (active) {
#pragma unroll
            for (int b = 0; b < 4; ++b) h2n[(bbase + b) * KP + jj] = h2v[b];
        }
        __syncthreads();  // publish h2[t]
        cur ^= 1;
    }

    // ================= FC head: out[b] = h2[T-1] . fc_w + fc_b =================
    if (tid < NB) {
        const float* h2f = h2b + cur * NB * KP + tid * KP;
        float s = fc_b[0];
        for (int j = 0; j < HID; ++j) s += h2f[j] * fc_w[j];
        out[b0 + tid] = s;
    }
}

extern "C" void kernel_launch(void* const* d_in, const int* in_sizes, int n_in,
                              void* d_out, int out_size, void* d_ws, size_t ws_size,
                              hipStream_t stream) {
    const float* x     = (const float*)d_in[0];
    const float* w_ih0 = (const float*)d_in[1];
    const float* w_hh0 = (const float*)d_in[2];
    const float* b_ih0 = (const float*)d_in[3];
    const float* b_hh0 = (const float*)d_in[4];
    const float* w_ih1 = (const float*)d_in[5];
    const float* w_hh1 = (const float*)d_in[6];
    const float* b_ih1 = (const float*)d_in[7];
    const float* b_hh1 = (const float*)d_in[8];
    const float* fc_w  = (const float*)d_in[9];
    const float* fc_b  = (const float*)d_in[10];
    float* out = (float*)d_out;

    const int B = in_sizes[0] / SEQ;  // 4096
    const size_t shmem =
        (size_t)(3 * GATES * KP + 4 * NB * KP + NB * XT) * sizeof(float);  // ~140 KB

    // host-side, idempotent, not a stream op -> graph-capture safe
    hipFuncSetAttribute((const void*)lstm2_fc_kernel,
                        hipFuncAttributeMaxDynamicSharedMemorySize, (int)shmem);

    lstm2_fc_kernel<<<B / NB, NTHREADS, shmem, stream>>>(
        x, w_ih0, w_hh0, b_ih0, b_hh0, w_ih1, w_hh1, b_ih1, b_hh1, fc_w, fc_b, out);
}

// Round 2
// 1236.055 us; speedup vs baseline: 4.8082x; 4.8082x over previous
//
#include <hip/hip_runtime.h>

// 2-layer LSTM (H=50) + FC head. MFMA fp16 formulation.
// B=4096, T=512. Grid = 256 blocks x 256 threads (4 waves); NB=16 batch/block.
// Per step: gates[16][200] = h @ W^T via mfma_f32_16x16x32_f16, weights live in
// VGPR B-fragments (loaded once), h1/h2 live in LDS in A-fragment layout
// (XOR-swizzled chunks), gates in LDS C-layout. Biases + x-term fold into the
// fp32 accumulator init. c1/c2 stay in registers of the elementwise threads.

#define HID 50
#define SEQ 512
#define NB 16
#define NTHREADS 256
#define GP 260            // gates row stride (floats): 2-way banks on C-writes
#define XP 516            // xs row stride (floats)

typedef _Float16 f16x8 __attribute__((ext_vector_type(8)));
typedef float    f32x4 __attribute__((ext_vector_type(4)));

__device__ __forceinline__ float sigf(float x) {
    return 1.0f / (1.0f + __expf(-x));
}
__device__ __forceinline__ float tanh_fast(float x) {
    return 2.0f / (1.0f + __expf(-2.0f * x)) - 1.0f;  // saturates correctly
}

// h-buffer chunk index: [kt][q][m^(q+4kt)] of 16B (8 half) chunks.
// Reader (A-frag, lane m=l15, quad qq): chunk = kt*64 + qq*16 + (m ^ (qq+4kt))
//   -> 64 lanes read 64 distinct contiguous chunks: conflict-free ds_read_b128.
// Writer (unit j, batch b): kt=j>>5, qh=(j>>3)&3, e=j&7:
//   chunk = kt*64 + qh*16 + (b ^ (qh+4kt)), half offset e.
__device__ __forceinline__ int hchunk(int kt, int qh, int b) {
    return kt * 64 + qh * 16 + (b ^ (qh + 4 * kt));
}

__global__ __launch_bounds__(NTHREADS, 1)
void lstm2_fc_mfma(const float* __restrict__ x,
                   const float* __restrict__ w_ih0,
                   const float* __restrict__ w_hh0,
                   const float* __restrict__ b_ih0,
                   const float* __restrict__ b_hh0,
                   const float* __restrict__ w_ih1,
                   const float* __restrict__ w_hh1,
                   const float* __restrict__ b_ih1,
                   const float* __restrict__ b_hh1,
                   const float* __restrict__ fc_w,
                   const float* __restrict__ fc_b,
                   float* __restrict__ out)
{
    __shared__ float xs[NB * XP];        // 33.0 KB  x for all 512 steps
    __shared__ float gates[NB * GP];     // 16.6 KB  C-layout gate preacts
    __shared__ f16x8 h1f[128];           //  2 KB    h1 in A-frag layout
    __shared__ f16x8 h2f[128];           //  2 KB    h2 in A-frag layout

    const int tid = threadIdx.x;
    const int b0  = blockIdx.x * NB;
    const int w   = tid >> 6;            // wave id 0..3
    const int l15 = tid & 15;            // MFMA lane column
    const int qq  = (tid >> 4) & 3;      // MFMA lane quad

    // ---- stage x into LDS (coalesced float4) ----
    for (int idx = tid; idx < NB * 128; idx += NTHREADS) {
        const int b  = idx >> 7;
        const int t4 = idx & 127;
        *(float4*)&xs[b * XP + t4 * 4] =
            *(const float4*)&x[(size_t)(b0 + b) * SEQ + t4 * 4];
    }
    // ---- zero h buffers ----
    if (tid < 128) { f16x8 z = {}; h1f[tid] = z; }
    else           { f16x8 z = {}; h2f[tid - 128] = z; }

    // ---- load weight B-fragments into registers (one-time) ----
    // B-operand: lane holds W[n = T*16 + l15][k = kt*32 + qq*8 + j], j=0..7
    const float* mats[3] = { w_hh0, w_ih1, w_hh1 };
    f16x8 wf[3][4][2];
    float wx0t[4], bAt[4], bBt[4];
#pragma unroll
    for (int i = 0; i < 4; ++i) {
        const int  T   = w * 4 + i;          // 16 N-tiles over 4 waves
        const int  n   = T * 16 + l15;
        const bool nok = (n < 4 * HID);
        wx0t[i] = nok ? w_ih0[n] : 0.0f;
        bAt[i]  = nok ? (b_ih0[n] + b_hh0[n]) : 0.0f;
        bBt[i]  = nok ? (b_ih1[n] + b_hh1[n]) : 0.0f;
#pragma unroll
        for (int mi = 0; mi < 3; ++mi) {
#pragma unroll
            for (int kt = 0; kt < 2; ++kt) {
                f16x8 f;
#pragma unroll
                for (int j = 0; j < 8; ++j) {
                    const int k = kt * 32 + qq * 8 + j;
                    const float v = (nok && k < HID) ? mats[mi][n * HID + k] : 0.0f;
                    f[j] = (_Float16)v;
                }
                wf[mi][i][kt] = f;
            }
        }
    }

    // ---- elementwise thread mapping: unit j = tid&63, batch group = wave ----
    const int  jslot  = tid & 63;
    const bool active = (jslot < HID);
    const int  jj     = active ? jslot : 0;
    const int  bbase  = w * 4;               // 4 batches per thread
    const int  ekt    = jj >> 5;
    const int  eqh    = (jj >> 3) & 3;
    const int  ee     = jj & 7;
    _Float16*  h1e    = (_Float16*)h1f;
    _Float16*  h2e    = (_Float16*)h2f;

    float c1[4] = {0.f, 0.f, 0.f, 0.f};
    float c2[4] = {0.f, 0.f, 0.f, 0.f};

    __syncthreads();   // xs, h zeros visible

    for (int t = 0; t < SEQ; ++t) {
        // ============ Phase A: L1 MFMA  gates = h1 @ w_hh0^T + x*wx + bA ====
        {
            const f16x8 a0 = h1f[qq * 16 + (l15 ^ qq)];
            const f16x8 a1 = h1f[64 + qq * 16 + (l15 ^ (qq + 4))];
            float xv[4];
#pragma unroll
            for (int r = 0; r < 4; ++r) xv[r] = xs[(qq * 4 + r) * XP + t];
#pragma unroll
            for (int i = 0; i < 4; ++i) {
                f32x4 acc;
#pragma unroll
                for (int r = 0; r < 4; ++r) acc[r] = xv[r] * wx0t[i] + bAt[i];
                acc = __builtin_amdgcn_mfma_f32_16x16x32_f16(a0, wf[0][i][0], acc, 0, 0, 0);
                acc = __builtin_amdgcn_mfma_f32_16x16x32_f16(a1, wf[0][i][1], acc, 0, 0, 0);
                const int base = (w * 4 + i) * 16 + l15;
#pragma unroll
                for (int r = 0; r < 4; ++r) gates[(qq * 4 + r) * GP + base] = acc[r];
            }
        }
        __syncthreads();

        // ============ Phase B: L1 elementwise -> h1f ============
        if (active) {
#pragma unroll
            for (int r = 0; r < 4; ++r) {
                const int b = bbase + r;
                const float gi = gates[b * GP + jj];
                const float gf = gates[b * GP + HID + jj];
                const float gg = gates[b * GP + 2 * HID + jj];
                const float go = gates[b * GP + 3 * HID + jj];
                const float ii = sigf(gi);
                const float ff = sigf(gf);
                const float g2 = tanh_fast(gg);
                const float oo = sigf(go);
                c1[r] = ff * c1[r] + ii * g2;
                const float h = oo * tanh_fast(c1[r]);
                h1e[hchunk(ekt, eqh, b) * 8 + ee] = (_Float16)h;
            }
        }
        __syncthreads();

        // ============ Phase C: L2 MFMA  gates = h1@w_ih1^T + h2@w_hh1^T + bB
        {
            const f16x8 p0 = h1f[qq * 16 + (l15 ^ qq)];
            const f16x8 p1 = h1f[64 + qq * 16 + (l15 ^ (qq + 4))];
            const f16x8 s0 = h2f[qq * 16 + (l15 ^ qq)];
            const f16x8 s1 = h2f[64 + qq * 16 + (l15 ^ (qq + 4))];
#pragma unroll
            for (int i = 0; i < 4; ++i) {
                f32x4 acc;
#pragma unroll
                for (int r = 0; r < 4; ++r) acc[r] = bBt[i];
                acc = __builtin_amdgcn_mfma_f32_16x16x32_f16(p0, wf[1][i][0], acc, 0, 0, 0);
                acc = __builtin_amdgcn_mfma_f32_16x16x32_f16(p1, wf[1][i][1], acc, 0, 0, 0);
                acc = __builtin_amdgcn_mfma_f32_16x16x32_f16(s0, wf[2][i][0], acc, 0, 0, 0);
                acc = __builtin_amdgcn_mfma_f32_16x16x32_f16(s1, wf[2][i][1], acc, 0, 0, 0);
                const int base = (w * 4 + i) * 16 + l15;
#pragma unroll
                for (int r = 0; r < 4; ++r) gates[(qq * 4 + r) * GP + base] = acc[r];
            }
        }
        __syncthreads();

        // ============ Phase D: L2 elementwise -> h2f ============
        if (active) {
#pragma unroll
            for (int r = 0; r < 4; ++r) {
                const int b = bbase + r;
                const float gi = gates[b * GP + jj];
                const float gf = gates[b * GP + HID + jj];
                const float gg = gates[b * GP + 2 * HID + jj];
                const float go = gates[b * GP + 3 * HID + jj];
                const float ii = sigf(gi);
                const float ff = sigf(gf);
                const float g2 = tanh_fast(gg);
                const float oo = sigf(go);
                c2[r] = ff * c2[r] + ii * g2;
                const float h = oo * tanh_fast(c2[r]);
                h2e[hchunk(ekt, eqh, b) * 8 + ee] = (_Float16)h;
            }
        }
        __syncthreads();
    }

    // ============ FC head: out[b] = h2[T-1] . fc_w + fc_b ============
    if (tid < NB) {
        const int b = tid;
        float s = fc_b[0];
        for (int j = 0; j < HID; ++j) {
            const int kt = j >> 5, qh = (j >> 3) & 3, e = j & 7;
            s += fc_w[j] * (float)h2e[hchunk(kt, qh, b) * 8 + e];
        }
        out[b0 + b] = s;
    }
}

extern "C" void kernel_launch(void* const* d_in, const int* in_sizes, int n_in,
                              void* d_out, int out_size, void* d_ws, size_t ws_size,
                              hipStream_t stream) {
    const float* x     = (const float*)d_in[0];
    const float* w_ih0 = (const float*)d_in[1];
    const float* w_hh0 = (const float*)d_in[2];
    const float* b_ih0 = (const float*)d_in[3];
    const float* b_hh0 = (const float*)d_in[4];
    const float* w_ih1 = (const float*)d_in[5];
    const float* w_hh1 = (const float*)d_in[6];
    const float* b_ih1 = (const float*)d_in[7];
    const float* b_hh1 = (const float*)d_in[8];
    const float* fc_w  = (const float*)d_in[9];
    const float* fc_b  = (const float*)d_in[10];
    float* out = (float*)d_out;

    const int B = in_sizes[0] / SEQ;  // 4096

    lstm2_fc_mfma<<<B / NB, NTHREADS, 0, stream>>>(
        x, w_ih0, w_hh0, b_ih0, b_hh0, w_ih1, w_hh1, b_ih1, b_hh1, fc_w, fc_b, out);
}